// Round 9
// baseline (250.145 us; speedup 1.0000x reference)
//
#include <hip/hip_runtime.h>
#include <math.h>

// FastRadonTransform via LDS-staged rotated-tile sampling, v7.
// fx = A + w*cos + h*sin ; fy = Bc - w*sin + h*cos (exact, H==W, align_corners).
// Stage 48row x 52col (stride 54) window per channel. Bank = (22*ly + lx) mod 32
// (stride 54 = 22 mod 32): additive row-drift alone; the v6 XOR is dropped to
// shrink LDS 39.2->31.1 KB => 5 blocks/CU (was 4). Resonance c==22s only in a
// ~1-deg band near theta=2.6deg (2/360 block-angles, acceptable); theta~49deg
// crossing is a free 2-way. Angle-adaptive lane mapping kept (lanes walk w when
// |cos|>=|sin| else h -> per-lane x-step >= 0.707). Staging: 13 float4 groups
// per row (52 cols), pure dwordx4 + b128 LDS writes on interior windows.

constexpr int B = 2, C = 3, H = 384, W = 384, K = 180;
constexpr int TILE = 32;
constexpr int NTW  = W / TILE;      // 12
constexpr int NTH  = H / TILE;      // 12
constexpr int ROWS = 48;
constexpr int BBS  = 54;            // row stride (54 mod 32 = 22); data cols 0..51
constexpr int CHS  = ROWS * BBS;    // 2592 floats = 10368 B per channel

struct Cat { int stage; int xal; int ym; };

__device__ __forceinline__ Cat tile_cat(float A, float Bc, float sth, float cth,
                                        int h0, int tw) {
    const float w0f = (float)(tw * TILE), w1f = w0f + (TILE - 1);
    const float h0f = (float)h0,          h1f = h0f + (TILE - 1);
    const float minfx = A  + fminf(w0f * cth, w1f * cth) + fminf(h0f * sth, h1f * sth);
    const float minfy = Bc + fminf(-w0f * sth, -w1f * sth) + fminf(h0f * cth, h1f * cth);
    Cat c;
    const int xm = (int)floorf(minfx) - 1;
    c.ym  = (int)floorf(minfy) - 1;
    c.xal = xm & ~3;
    const bool skip = (xm + 47 < 0) | (xm > W - 1) | (c.ym + 47 < 0) | (c.ym > H - 1);
    c.stage = skip ? 0 : 1;
    return c;
}

// Staging: u = tid + 256j (j<3), r = u>>4 in [0,48), g = u&15; active g<13.
// Window: rows ym..ym+47, cols xal..xal+51 (xal 4-aligned).
__device__ __forceinline__ void issue_loads(const float* __restrict__ img,
                                            int tid, int xal, int ym,
                                            float4 (&pf)[C][3]) {
    #pragma unroll
    for (int c = 0; c < C; ++c) {
        const float* __restrict__ plane = img + c * (H * W);
        #pragma unroll
        for (int j = 0; j < 3; ++j) {
            const int u = tid + 256 * j;
            const int r = u >> 4;
            const int g = u & 15;
            if (g < 13) {
                const int gy = min(max(ym + r, 0), H - 1);
                const int gx = min(max(xal + 4 * g, 0), W - 4);  // stays 4-aligned
                pf[c][j] = *reinterpret_cast<const float4*>(plane + gy * W + gx);
            }
        }
    }
}

__device__ __forceinline__ void write_stage(const float* __restrict__ img,
                                            float* __restrict__ sm,
                                            int tid, int xal, int ym,
                                            const float4 (&pf)[C][3]) {
    const bool interior = (ym >= 0) & (ym <= H - ROWS) &
                          (xal >= 0) & (xal <= W - 52);
    #pragma unroll
    for (int c = 0; c < C; ++c) {
        const float* __restrict__ plane = img + c * (H * W);
        #pragma unroll
        for (int j = 0; j < 3; ++j) {
            const int u = tid + 256 * j;
            const int r = u >> 4;
            const int g = u & 15;
            if (g >= 13) continue;
            const int bs = c * CHS + r * BBS + 4 * g;
            const float4 v = pf[c][j];
            if (interior) {
                *reinterpret_cast<float4*>(sm + bs) = v;
            } else {
                const int gy = ym + r;
                const int gx = xal + 4 * g;
                const bool rowok = ((unsigned)gy < (unsigned)H);
                if (rowok && gx >= 0 && gx <= W - 4) {
                    *reinterpret_cast<float4*>(sm + bs) = v;
                } else {
                    const int gyc = min(max(gy, 0), H - 1);
                    #pragma unroll
                    for (int e = 0; e < 4; ++e) {
                        const int gxe = gx + e;
                        const bool ok = rowok && ((unsigned)gxe < (unsigned)W);
                        const int gxc = min(max(gxe, 0), W - 1);
                        const float t = plane[gyc * W + gxc];
                        sm[bs + e] = ok ? t : 0.0f;
                    }
                }
            }
        }
    }
}

__global__ __launch_bounds__(256) void radon_tile(
    const float* __restrict__ x,       // (B,C,H,W)
    const float* __restrict__ angles,  // (B,K)
    float* __restrict__ out)           // (B,C,H,K)
{
    __shared__ __align__(16) float sm[C * CHS];   // 31104 B -> 5 blocks/CU

    const int bid = blockIdx.x;
    const int th  = bid % NTH;
    const int bk  = bid / NTH;
    const int k   = bk % K;
    const int b   = bk / K;

    const int tid = threadIdx.x;
    const int u1  = tid & 31;          // fine lane index (32 values)
    const int u8  = tid >> 5;          // group index (8 values)

    const float theta = angles[b * K + k] * (3.14159265358979323846f / 180.0f);
    float sth, cth;
    sincosf(theta, &sth, &cth);

    const float A  = 0.5f * (W - 1) * (1.0f - cth - sth);
    const float Bc = 0.5f * (H - 1) * (1.0f + sth - cth);

    // mapping select (block-uniform): lanes walk the axis with x-step >= .707
    const bool mapB = fabsf(sth) > fabsf(cth);
    const int wofs = mapB ? u8 : u1;
    const int hofs = mapB ? u1 : u8;
    const float dix = mapB ? 8.0f * cth :  8.0f * sth;
    const float diy = mapB ? -8.0f * sth : 8.0f * cth;

    const int h0 = th * TILE;
    const float hf = (float)(h0 + hofs);

    const float* __restrict__ img = x + (size_t)b * (C * H * W);

    float acc[4][C];
    #pragma unroll
    for (int i = 0; i < 4; ++i)
        #pragma unroll
        for (int c = 0; c < C; ++c) acc[i][c] = 0.0f;

    float4 pf[C][3];
    Cat cur = tile_cat(A, Bc, sth, cth, h0, 0);
    if (cur.stage) issue_loads(img, tid, cur.xal, cur.ym, pf);

    for (int tw = 0; tw < NTW; ++tw) {
        Cat nxt; nxt.stage = 0; nxt.xal = 0; nxt.ym = 0;
        if (tw + 1 < NTW) nxt = tile_cat(A, Bc, sth, cth, h0, tw + 1);

        if (cur.stage) {
            __syncthreads();                       // prior sampling done
            write_stage(img, sm, tid, cur.xal, cur.ym, pf);
        }
        if (nxt.stage) issue_loads(img, tid, nxt.xal, nxt.ym, pf);  // overlap
        if (cur.stage) {
            __syncthreads();                       // LDS tile ready
            // window-local seeds: lx/ly come straight from floorf
            const float wf = (float)(tw * TILE + wofs);
            float fx = fmaf(hf, sth, fmaf(wf,  cth, A)) - (float)cur.xal;
            float fy = fmaf(hf, cth, fmaf(wf, -sth, Bc)) - (float)cur.ym;
            #pragma unroll
            for (int i = 0; i < 4; ++i) {
                const float xf = floorf(fx), yf = floorf(fy);
                const int lx = (int)xf;            // [1, 50] <= 51
                const int ly = (int)yf;            // [1, 46] < 48
                const float wx1 = fx - xf, wy1 = fy - yf;
                const float wx0 = 1.0f - wx1, wy0 = 1.0f - wy1;
                const float w00 = wy0 * wx0, w01 = wy0 * wx1;
                const float w10 = wy1 * wx0, w11 = wy1 * wx1;
                const int s00 = ly * BBS + lx;
                const int s01 = s00 + 1;
                const int s10 = s00 + BBS;
                const int s11 = s10 + 1;
                #pragma unroll
                for (int c = 0; c < C; ++c) {
                    const int cb = c * CHS;        // folds into ds_read offset:
                    const float p00 = sm[cb + s00];
                    const float p01 = sm[cb + s01];
                    const float p10 = sm[cb + s10];
                    const float p11 = sm[cb + s11];
                    acc[i][c] = fmaf(w00, p00, fmaf(w01, p01,
                                fmaf(w10, p10, fmaf(w11, p11, acc[i][c]))));
                }
                fx += dix; fy += diy;
            }
        }
        cur = nxt;
    }

    if (!mapB) {
        // reduce over the 32 u1-lanes (w); xor masks <32 stay in each half
        #pragma unroll
        for (int i = 0; i < 4; ++i) {
            #pragma unroll
            for (int c = 0; c < C; ++c) {
                float s = acc[i][c];
                #pragma unroll
                for (int m = 16; m >= 1; m >>= 1) s += __shfl_xor(s, m, 64);
                if (u1 == 0) {
                    const int h = h0 + u8 + 8 * i;
                    out[((size_t)(b * C + c) * H + h) * K + k] = s;
                }
            }
        }
    } else {
        // each thread owns one h = h0+u1; sum its 4 w-chunks, then reduce
        // the 8 u8-groups through LDS (reused; sync before overwrite).
        __syncthreads();
        #pragma unroll
        for (int c = 0; c < C; ++c) {
            const float s = (acc[0][c] + acc[1][c]) + (acc[2][c] + acc[3][c]);
            sm[(c * 8 + u8) * 32 + u1] = s;
        }
        __syncthreads();
        if (tid < C * 32) {
            const int c = tid >> 5;
            const int l = tid & 31;
            float s = 0.0f;
            #pragma unroll
            for (int g = 0; g < 8; ++g) s += sm[(c * 8 + g) * 32 + l];
            out[((size_t)(b * C + c) * H + (h0 + l)) * K + k] = s;
        }
    }
}

extern "C" void kernel_launch(void* const* d_in, const int* in_sizes, int n_in,
                              void* d_out, int out_size, void* d_ws, size_t ws_size,
                              hipStream_t stream) {
    const float* x      = (const float*)d_in[0];
    const float* angles = (const float*)d_in[1];
    float* out          = (float*)d_out;

    radon_tile<<<B * K * NTH, 256, 0, stream>>>(x, angles, out);  // 4320 blocks
}